// Round 7
// baseline (592.764 us; speedup 1.0000x reference)
//
#include <hip/hip_runtime.h>
#include <hip/hip_bf16.h>
#include <math.h>

#define NN 25000
#define NE 250000
#define DD 64
#define HH 4
#define NGROUP (NE / 16)   // 15625 16-edge groups

typedef __attribute__((ext_vector_type(8))) short bf16x8;
typedef __attribute__((ext_vector_type(4))) float f32x4;

#define WT_LD 136   // 128 + 8 pad (shorts) -> 272B row stride, 2-way LDS conflict (free)

__device__ __forceinline__ float softplus_f(float x) {
    return fmaxf(x, 0.0f) + __logf(1.0f + __expf(-fabsf(x)));
}

__device__ __forceinline__ unsigned short f2bf(float f) {
    __hip_bfloat16 h = __float2bfloat16(f);
    unsigned short u;
    __builtin_memcpy(&u, &h, 2);
    return u;
}

__device__ __forceinline__ float bf2f(unsigned short u) {
    return __uint_as_float(((unsigned int)u) << 16);
}

// Load 8 consecutive floats, split each into bf16 hi + bf16 lo (compensated).
__device__ __forceinline__ void load8(const float* p, bf16x8& hi, bf16x8& lo) {
    float4 a = *(const float4*)p;
    float4 b = *(const float4*)(p + 4);
    float v[8] = {a.x, a.y, a.z, a.w, b.x, b.y, b.z, b.w};
#pragma unroll
    for (int i = 0; i < 8; ++i) {
        unsigned short h = f2bf(v[i]);
        hi[i] = (short)h;
        lo[i] = (short)f2bf(v[i] - bf2f(h));
    }
}

// One wave = 16 edges, mfma_f32_16x16x32_bf16, A gathered straight into lanes,
// W^T bf16 in LDS (one copy shared by the block's 8 waves).
// OCCUPANCY NOTE (r5/r6 lesson): gfx950 unified VGPR/AGPR file; keep live
// accumulators to 8 f32x4 by consuming each head-group immediately.
// (512,4) verified: VGPR=64, no spill, 16 waves/CU, 166us.
__global__ __launch_bounds__(512, 4)
void k_edge(const float* __restrict__ x, const float* __restrict__ ea,
            const float* __restrict__ W, const float* __restrict__ att,
            const float* __restrict__ bn_g, const float* __restrict__ bn_b,
            const float* __restrict__ bn_m, const float* __restrict__ bn_v,
            const int* __restrict__ eidx,
            unsigned short* __restrict__ outj,
            float* __restrict__ expa)
{
    __shared__ unsigned short Wsh[256 * WT_LD];  // W^T bf16 [n][k], padded
    __shared__ float attI[256], attJ[256];

    const int tid = threadIdx.x;
    const int lane = tid & 63;
    const int q = lane >> 4;      // quad 0..3
    const int r = lane & 15;

    // Stage W^T (coalesced read of W[k*256+n], n fast-varying).
    for (int idx = tid; idx < 32768; idx += 512) {
        int k = idx >> 8, n = idx & 255;
        Wsh[n * WT_LD + k] = f2bf(W[idx]);
    }
    if (tid < 256) {
        int c = tid;
        attI[c] = att[(c >> 6) * 128 + (c & 63)];
        attJ[c] = att[(c >> 6) * 128 + 64 + (c & 63)];
    }
    float bnsc[HH], bnsh[HH];
#pragma unroll
    for (int t = 0; t < HH; ++t) {
        float inv = rsqrtf(bn_v[t] + 1e-5f);
        bnsc[t] = bn_g[t] * inv;
        bnsh[t] = bn_b[t] - bn_m[t] * bn_g[t] * inv;
    }
    __syncthreads();

    const int gw = blockIdx.x * 8 + (tid >> 6);
    const int nw = gridDim.x * 8;

    for (int g = gw; g < NGROUP; g += nw) {
        const int e0 = g * 16;
        const int ei = eidx[e0 + r];
        const int ej = eidx[NE + e0 + r];
        const float* xi = x + (size_t)ei * DD;
        const float* xj = x + (size_t)ej * DD;
        const float* ev = ea + (size_t)(e0 + r) * DD;

        bf16x8 Ahi[6], Alo[6];  // 0,1: x_i k-tiles; 2,3: x_j; 4,5: ea
        load8(xi + q * 8,      Ahi[0], Alo[0]);
        load8(xi + 32 + q * 8, Ahi[1], Alo[1]);
        load8(xj + q * 8,      Ahi[2], Alo[2]);
        load8(xj + 32 + q * 8, Ahi[3], Alo[3]);
        load8(ev + q * 8,      Ahi[4], Alo[4]);
        load8(ev + 32 + q * 8, Ahi[5], Alo[5]);

        float lg[4][4];  // [reg][head]
#pragma unroll
        for (int a = 0; a < 4; ++a)
#pragma unroll
            for (int b = 0; b < 4; ++b) lg[a][b] = 0.f;

        // ---- fused MFMA + epilogue: iteration nt handles col-tiles
        // {nt+4h | h=0..3} (one col per head per lane -> one ushort4 store) ----
#pragma unroll
        for (int nt = 0; nt < 4; ++nt) {
            f32x4 ai[4], aj[4];
#pragma unroll
            for (int h = 0; h < 4; ++h) {
                ai[h] = (f32x4){0.f, 0.f, 0.f, 0.f};
                aj[h] = (f32x4){0.f, 0.f, 0.f, 0.f};
            }
#pragma unroll
            for (int h = 0; h < 4; ++h) {
                const unsigned short* bp = &Wsh[((nt + 4 * h) * 16 + r) * WT_LD + q * 8];
#pragma unroll
                for (int kt = 0; kt < 4; ++kt) {
                    bf16x8 bf = *(const bf16x8*)(bp + kt * 32);
                    const int fi = (kt < 2) ? kt : kt + 2;  // x_i, x_i, ea, ea
                    const int fj = kt + 2;                  // x_j, x_j, ea, ea
                    ai[h] = __builtin_amdgcn_mfma_f32_16x16x32_bf16(Ahi[fi], bf, ai[h], 0, 0, 0);
                    ai[h] = __builtin_amdgcn_mfma_f32_16x16x32_bf16(Alo[fi], bf, ai[h], 0, 0, 0);
                    aj[h] = __builtin_amdgcn_mfma_f32_16x16x32_bf16(Ahi[fj], bf, aj[h], 0, 0, 0);
                    aj[h] = __builtin_amdgcn_mfma_f32_16x16x32_bf16(Alo[fj], bf, aj[h], 0, 0, 0);
                }
            }
            // consume: softplus, att partials, pack+store outj (acc dies here)
            const int dbase = nt * 16 + r;   // dim index d for this lane
#pragma unroll
            for (int reg = 0; reg < 4; ++reg) {
                ushort4 pk;
                unsigned short* pkp = (unsigned short*)&pk;
#pragma unroll
                for (int h = 0; h < 4; ++h) {
                    const int c = dbase + 64 * h;
                    float spi = softplus_f(ai[h][reg]);
                    float spj = softplus_f(aj[h][reg]);
                    lg[reg][h] += spi * attI[c] + spj * attJ[c];
                    pkp[h] = f2bf(spj);
                }
                const unsigned e = (unsigned)(e0 + q * 4 + reg);
                *(ushort4*)&outj[e * 256 + dbase * 4] = pk;
            }
        }

        // ---- logit reduce + BN + exp ----
#pragma unroll
        for (int off = 1; off < 16; off <<= 1) {
#pragma unroll
            for (int a = 0; a < 4; ++a)
#pragma unroll
                for (int b = 0; b < 4; ++b)
                    lg[a][b] += __shfl_xor(lg[a][b], off, 64);
        }
        if (r < 4) {  // lane r handles head r for its quad's 4 edges
#pragma unroll
            for (int reg = 0; reg < 4; ++reg) {
                const int e = e0 + q * 4 + reg;
                expa[e * 4 + r] = __expf(softplus_f(fmaf(lg[reg][r], bnsc[r], bnsh[r])));
            }
        }
    }
}

// ---- counting sort of edges by target node ----
__global__ __launch_bounds__(256)
void k_hist(const int* __restrict__ eidx, int* __restrict__ cnt) {
    const int e = blockIdx.x * 256 + threadIdx.x;
    if (e < NE) atomicAdd(&cnt[eidx[e]], 1);
}

// Single-block exclusive scan over 25K bins -> offs[0..NN], cursor copy.
__global__ __launch_bounds__(1024)
void k_scan(const int* __restrict__ cnt, int* __restrict__ offs,
            int* __restrict__ cursor) {
    __shared__ int sdata[1024];
    const int tid = threadIdx.x;
    int running = 0;
    for (int chunk = 0; chunk < (NN + 1023) / 1024; ++chunk) {
        const int i = chunk * 1024 + tid;
        int v = (i < NN) ? cnt[i] : 0;
        sdata[tid] = v;
        __syncthreads();
        for (int off = 1; off < 1024; off <<= 1) {
            int t = (tid >= off) ? sdata[tid - off] : 0;
            __syncthreads();
            sdata[tid] += t;
            __syncthreads();
        }
        if (i < NN) {
            int excl = running + sdata[tid] - v;
            offs[i] = excl;
            cursor[i] = excl;
        }
        running += sdata[1023];
        __syncthreads();
    }
    if (tid == 0) offs[NN] = NE;
}

__global__ __launch_bounds__(256)
void k_place(const int* __restrict__ eidx, int* __restrict__ cursor,
             int* __restrict__ perm) {
    const int e = blockIdx.x * 256 + threadIdx.x;
    if (e < NE) {
        const int pos = atomicAdd(&cursor[eidx[e]], 1);
        perm[pos] = e;
    }
}

// One wave per node, lane = dim d. Gathers this node's edges via CSR,
// computes denom inline, folds head-mean (0.25) + bias. NO atomics.
__global__ __launch_bounds__(256)
void k_aggr(const int* __restrict__ offs, const int* __restrict__ perm,
            const unsigned short* __restrict__ outj,
            const float* __restrict__ expa,
            const float* __restrict__ bias,
            float* __restrict__ out)
{
    const int n = blockIdx.x * 4 + (threadIdx.x >> 6);
    if (n >= NN) return;
    const int lane = threadIdx.x & 63;
    const int k0 = offs[n], k1 = offs[n + 1];
    float num0 = 0.f, num1 = 0.f, num2 = 0.f, num3 = 0.f;
    float den0 = 0.f, den1 = 0.f, den2 = 0.f, den3 = 0.f;
    for (int k = k0; k < k1; ++k) {
        const int e = perm[k];
        const float4 ex = *(const float4*)&expa[e * 4];
        const ushort4 v = *(const ushort4*)&outj[((unsigned)e << 8) | (lane << 2)];
        num0 += ex.x * bf2f(v.x);
        num1 += ex.y * bf2f(v.y);
        num2 += ex.z * bf2f(v.z);
        num3 += ex.w * bf2f(v.w);
        den0 += ex.x; den1 += ex.y; den2 += ex.z; den3 += ex.w;
    }
    float r = 0.f;
    r += (den0 > 0.f) ? num0 / den0 : 0.f;
    r += (den1 > 0.f) ? num1 / den1 : 0.f;
    r += (den2 > 0.f) ? num2 / den2 : 0.f;
    r += (den3 > 0.f) ? num3 / den3 : 0.f;
    out[n * DD + lane] = 0.25f * r + bias[lane];
}

extern "C" void kernel_launch(void* const* d_in, const int* in_sizes, int n_in,
                              void* d_out, int out_size, void* d_ws, size_t ws_size,
                              hipStream_t stream)
{
    (void)in_sizes; (void)n_in; (void)out_size; (void)ws_size;
    const float* x    = (const float*)d_in[0];
    const float* ea   = (const float*)d_in[1];
    const float* W    = (const float*)d_in[2];
    const float* att  = (const float*)d_in[3];
    const float* bias = (const float*)d_in[4];
    const float* bn_g = (const float*)d_in[5];
    const float* bn_b = (const float*)d_in[6];
    const float* bn_m = (const float*)d_in[7];
    const float* bn_v = (const float*)d_in[8];
    const int*   eidx = (const int*)d_in[9];
    float* out = (float*)d_out;

    // ws layout: outj bf16 [E][64][4] (128 MB) | expa f32 [E][4] (4 MB) |
    //            cnt [NN] | offs [NN+1] | cursor [NN] | perm [NE]  (~1.4 MB)
    char* ws = (char*)d_ws;
    unsigned short* outj = (unsigned short*)ws;
    float* expa = (float*)(ws + (size_t)NE * 256 * 2);
    int*   cnt    = (int*)(ws + (size_t)NE * 256 * 2 + (size_t)NE * 16);
    int*   offs   = cnt + NN;
    int*   cursor = offs + NN + 1;
    int*   perm   = cursor + NN;

    hipMemsetAsync(cnt, 0, NN * sizeof(int), stream);

    k_hist <<<dim3((NE + 255) / 256), dim3(256), 0, stream>>>(eidx, cnt);
    k_scan <<<dim3(1), dim3(1024), 0, stream>>>(cnt, offs, cursor);
    k_place<<<dim3((NE + 255) / 256), dim3(256), 0, stream>>>(eidx, cursor, perm);

    k_edge<<<dim3(512), dim3(512), 0, stream>>>(
        x, ea, W, att, bn_g, bn_b, bn_m, bn_v, eidx, outj, expa);

    k_aggr<<<dim3((NN + 3) / 4), dim3(256), 0, stream>>>(
        offs, perm, outj, expa, bias, out);
}

// Round 8
// 323.329 us; speedup vs baseline: 1.8333x; 1.8333x over previous
//
#include <hip/hip_runtime.h>
#include <hip/hip_bf16.h>
#include <math.h>

#define NN 25000
#define NE 250000
#define DD 64
#define HH 4
#define NGROUP (NE / 16)   // 15625 16-edge groups
#define NB 98              // ceil(NN/256) scan blocks

typedef __attribute__((ext_vector_type(8))) short bf16x8;
typedef __attribute__((ext_vector_type(4))) float f32x4;

#define WT_LD 136   // 128 + 8 pad (shorts) -> 272B row stride, 2-way LDS conflict (free)

__device__ __forceinline__ float softplus_f(float x) {
    return fmaxf(x, 0.0f) + __logf(1.0f + __expf(-fabsf(x)));
}

__device__ __forceinline__ unsigned short f2bf(float f) {
    __hip_bfloat16 h = __float2bfloat16(f);
    unsigned short u;
    __builtin_memcpy(&u, &h, 2);
    return u;
}

__device__ __forceinline__ float bf2f(unsigned short u) {
    return __uint_as_float(((unsigned int)u) << 16);
}

// Load 8 consecutive floats, split each into bf16 hi + bf16 lo (compensated).
__device__ __forceinline__ void load8(const float* p, bf16x8& hi, bf16x8& lo) {
    float4 a = *(const float4*)p;
    float4 b = *(const float4*)(p + 4);
    float v[8] = {a.x, a.y, a.z, a.w, b.x, b.y, b.z, b.w};
#pragma unroll
    for (int i = 0; i < 8; ++i) {
        unsigned short h = f2bf(v[i]);
        hi[i] = (short)h;
        lo[i] = (short)f2bf(v[i] - bf2f(h));
    }
}

// ===== k_edge: BYTE-IDENTICAL to the round-6 kernel that measured 166us =====
// (VGPR=64, FETCH 156MB, WRITE 227MB, MfmaUtil 16.8, occ 36%.)
// DO NOT TOUCH THE BODY: round 7 changed only the epilogue (removed the denom
// atomic) and the allocator spilled ~750MB of scratch -> 368us. The allocation
// is fragile exactly at the 128-unified-regs/wave boundary of (512,4).
__global__ __launch_bounds__(512, 4)
void k_edge(const float* __restrict__ x, const float* __restrict__ ea,
            const float* __restrict__ W, const float* __restrict__ att,
            const float* __restrict__ bn_g, const float* __restrict__ bn_b,
            const float* __restrict__ bn_m, const float* __restrict__ bn_v,
            const int* __restrict__ eidx,
            unsigned short* __restrict__ outj,
            float* __restrict__ expa, float* __restrict__ denom)
{
    __shared__ unsigned short Wsh[256 * WT_LD];  // W^T bf16 [n][k], padded
    __shared__ float attI[256], attJ[256];

    const int tid = threadIdx.x;
    const int lane = tid & 63;
    const int q = lane >> 4;      // quad 0..3
    const int r = lane & 15;

    // Stage W^T (coalesced read of W[k*256+n], n fast-varying).
    for (int idx = tid; idx < 32768; idx += 512) {
        int k = idx >> 8, n = idx & 255;
        Wsh[n * WT_LD + k] = f2bf(W[idx]);
    }
    if (tid < 256) {
        int c = tid;
        attI[c] = att[(c >> 6) * 128 + (c & 63)];
        attJ[c] = att[(c >> 6) * 128 + 64 + (c & 63)];
    }
    float bnsc[HH], bnsh[HH];
#pragma unroll
    for (int t = 0; t < HH; ++t) {
        float inv = rsqrtf(bn_v[t] + 1e-5f);
        bnsc[t] = bn_g[t] * inv;
        bnsh[t] = bn_b[t] - bn_m[t] * bn_g[t] * inv;
    }
    __syncthreads();

    const int gw = blockIdx.x * 8 + (tid >> 6);
    const int nw = gridDim.x * 8;

    for (int g = gw; g < NGROUP; g += nw) {
        const int e0 = g * 16;
        const int ei = eidx[e0 + r];
        const int ej = eidx[NE + e0 + r];
        const float* xi = x + (size_t)ei * DD;
        const float* xj = x + (size_t)ej * DD;
        const float* ev = ea + (size_t)(e0 + r) * DD;

        bf16x8 Ahi[6], Alo[6];  // 0,1: x_i k-tiles; 2,3: x_j; 4,5: ea
        load8(xi + q * 8,      Ahi[0], Alo[0]);
        load8(xi + 32 + q * 8, Ahi[1], Alo[1]);
        load8(xj + q * 8,      Ahi[2], Alo[2]);
        load8(xj + 32 + q * 8, Ahi[3], Alo[3]);
        load8(ev + q * 8,      Ahi[4], Alo[4]);
        load8(ev + 32 + q * 8, Ahi[5], Alo[5]);

        float lg[4][4];  // [reg][head]
#pragma unroll
        for (int a = 0; a < 4; ++a)
#pragma unroll
            for (int b = 0; b < 4; ++b) lg[a][b] = 0.f;

        // ---- fused MFMA + epilogue: iteration nt handles col-tiles
        // {nt+4h | h=0..3} (one col per head per lane -> one ushort4 store) ----
#pragma unroll
        for (int nt = 0; nt < 4; ++nt) {
            f32x4 ai[4], aj[4];
#pragma unroll
            for (int h = 0; h < 4; ++h) {
                ai[h] = (f32x4){0.f, 0.f, 0.f, 0.f};
                aj[h] = (f32x4){0.f, 0.f, 0.f, 0.f};
            }
#pragma unroll
            for (int h = 0; h < 4; ++h) {
                const unsigned short* bp = &Wsh[((nt + 4 * h) * 16 + r) * WT_LD + q * 8];
#pragma unroll
                for (int kt = 0; kt < 4; ++kt) {
                    bf16x8 bf = *(const bf16x8*)(bp + kt * 32);
                    const int fi = (kt < 2) ? kt : kt + 2;  // x_i, x_i, ea, ea
                    const int fj = kt + 2;                  // x_j, x_j, ea, ea
                    ai[h] = __builtin_amdgcn_mfma_f32_16x16x32_bf16(Ahi[fi], bf, ai[h], 0, 0, 0);
                    ai[h] = __builtin_amdgcn_mfma_f32_16x16x32_bf16(Alo[fi], bf, ai[h], 0, 0, 0);
                    aj[h] = __builtin_amdgcn_mfma_f32_16x16x32_bf16(Ahi[fj], bf, aj[h], 0, 0, 0);
                    aj[h] = __builtin_amdgcn_mfma_f32_16x16x32_bf16(Alo[fj], bf, aj[h], 0, 0, 0);
                }
            }
            // consume: softplus, att partials, pack+store outj (acc dies here)
            const int dbase = nt * 16 + r;   // dim index d for this lane
#pragma unroll
            for (int reg = 0; reg < 4; ++reg) {
                ushort4 pk;
                unsigned short* pkp = (unsigned short*)&pk;
#pragma unroll
                for (int h = 0; h < 4; ++h) {
                    const int c = dbase + 64 * h;
                    float spi = softplus_f(ai[h][reg]);
                    float spj = softplus_f(aj[h][reg]);
                    lg[reg][h] += spi * attI[c] + spj * attJ[c];
                    pkp[h] = f2bf(spj);
                }
                const unsigned e = (unsigned)(e0 + q * 4 + reg);
                *(ushort4*)&outj[e * 256 + dbase * 4] = pk;
            }
        }

        // ---- logit reduce + BN + exp + denom ----
#pragma unroll
        for (int off = 1; off < 16; off <<= 1) {
#pragma unroll
            for (int a = 0; a < 4; ++a)
#pragma unroll
                for (int b = 0; b < 4; ++b)
                    lg[a][b] += __shfl_xor(lg[a][b], off, 64);
        }
        float exv[4][4];
#pragma unroll
        for (int reg = 0; reg < 4; ++reg)
#pragma unroll
            for (int h = 0; h < 4; ++h)
                exv[reg][h] = __expf(softplus_f(fmaf(lg[reg][h], bnsc[h], bnsh[h])));

        if (r < 4) {  // lane r handles head r for its quad's 4 edges
#pragma unroll
            for (int reg = 0; reg < 4; ++reg) {
                const int e = e0 + q * 4 + reg;
                const int ii = eidx[e];
                expa[e * 4 + r] = exv[reg][r];
                atomicAdd(&denom[ii * 4 + r], exv[reg][r]);
            }
        }
    }
}

// ===== counting sort of edges by target node (multi-CU scan) =====
__global__ __launch_bounds__(256)
void k_hist(const int* __restrict__ eidx, int* __restrict__ cnt) {
    const int e = blockIdx.x * 256 + threadIdx.x;
    if (e < NE) atomicAdd(&cnt[eidx[e]], 1);
}

// Stage A: per-block (256-bin) local exclusive scan + block total.
__global__ __launch_bounds__(256)
void k_scanA(const int* __restrict__ cnt, int* __restrict__ offs,
             int* __restrict__ bsum) {
    __shared__ int s[256];
    const int tid = threadIdx.x;
    const int i = blockIdx.x * 256 + tid;
    int v = (i < NN) ? cnt[i] : 0;
    s[tid] = v;
    __syncthreads();
#pragma unroll
    for (int off = 1; off < 256; off <<= 1) {
        int t = (tid >= off) ? s[tid - off] : 0;
        __syncthreads();
        s[tid] += t;
        __syncthreads();
    }
    if (i < NN) offs[i] = s[tid] - v;          // local exclusive
    if (tid == 255) bsum[blockIdx.x] = s[255]; // block total
}

// Stage B: single block scans NB block totals -> exclusive bases.
__global__ __launch_bounds__(128)
void k_scanB(const int* __restrict__ bsum, int* __restrict__ bbase) {
    __shared__ int s[128];
    const int tid = threadIdx.x;
    int v = (tid < NB) ? bsum[tid] : 0;
    s[tid] = v;
    __syncthreads();
#pragma unroll
    for (int off = 1; off < 128; off <<= 1) {
        int t = (tid >= off) ? s[tid - off] : 0;
        __syncthreads();
        s[tid] += t;
        __syncthreads();
    }
    if (tid < NB) bbase[tid] = s[tid] - v;
}

// Stage C: add bases, produce final offs + cursor copy.
__global__ __launch_bounds__(256)
void k_scanC(int* __restrict__ offs, const int* __restrict__ bbase,
             int* __restrict__ cursor) {
    const int i = blockIdx.x * 256 + threadIdx.x;
    if (i < NN) {
        const int o = offs[i] + bbase[blockIdx.x];
        offs[i] = o;
        cursor[i] = o;
    }
    if (i == 0) offs[NN] = NE;
}

__global__ __launch_bounds__(256)
void k_place(const int* __restrict__ eidx, int* __restrict__ cursor,
             int* __restrict__ perm) {
    const int e = blockIdx.x * 256 + threadIdx.x;
    if (e < NE) {
        const int pos = atomicAdd(&cursor[eidx[e]], 1);
        perm[pos] = e;
    }
}

// One wave per node, lane = dim d. CSR gather over the node's edges; denom
// read from k_edge's atomic sum; head-mean (0.25) + bias folded. NO atomics.
__global__ __launch_bounds__(256)
void k_aggr(const int* __restrict__ offs, const int* __restrict__ perm,
            const unsigned short* __restrict__ outj,
            const float* __restrict__ expa,
            const float* __restrict__ denom,
            const float* __restrict__ bias,
            float* __restrict__ out)
{
    const int n = blockIdx.x * 4 + (threadIdx.x >> 6);
    if (n >= NN) return;
    const int lane = threadIdx.x & 63;
    const int k0 = offs[n], k1 = offs[n + 1];
    const float4 dv = *(const float4*)&denom[n * 4];
    float num0 = 0.f, num1 = 0.f, num2 = 0.f, num3 = 0.f;

    if (k0 < k1) {
        int e = perm[k0];
        float4 ex = *(const float4*)&expa[e * 4];
        ushort4 v = *(const ushort4*)&outj[((unsigned)e << 8) | (lane << 2)];
        for (int k = k0; k < k1; ++k) {
            float4 exc = ex; ushort4 vc = v;
            if (k + 1 < k1) {   // 1-deep pipeline on the perm->data chain
                const int e2 = perm[k + 1];
                ex = *(const float4*)&expa[e2 * 4];
                v  = *(const ushort4*)&outj[((unsigned)e2 << 8) | (lane << 2)];
            }
            num0 += exc.x * bf2f(vc.x);
            num1 += exc.y * bf2f(vc.y);
            num2 += exc.z * bf2f(vc.z);
            num3 += exc.w * bf2f(vc.w);
        }
    }
    float r = 0.f;
    r += (dv.x > 0.f) ? num0 / dv.x : 0.f;
    r += (dv.y > 0.f) ? num1 / dv.y : 0.f;
    r += (dv.z > 0.f) ? num2 / dv.z : 0.f;
    r += (dv.w > 0.f) ? num3 / dv.w : 0.f;
    out[n * DD + lane] = 0.25f * r + bias[lane];
}

extern "C" void kernel_launch(void* const* d_in, const int* in_sizes, int n_in,
                              void* d_out, int out_size, void* d_ws, size_t ws_size,
                              hipStream_t stream)
{
    (void)in_sizes; (void)n_in; (void)out_size; (void)ws_size;
    const float* x    = (const float*)d_in[0];
    const float* ea   = (const float*)d_in[1];
    const float* W    = (const float*)d_in[2];
    const float* att  = (const float*)d_in[3];
    const float* bias = (const float*)d_in[4];
    const float* bn_g = (const float*)d_in[5];
    const float* bn_b = (const float*)d_in[6];
    const float* bn_m = (const float*)d_in[7];
    const float* bn_v = (const float*)d_in[8];
    const int*   eidx = (const int*)d_in[9];
    float* out = (float*)d_out;

    // ws layout: outj bf16 [E][64][4] (128 MB) | expa f32 [E][4] (4 MB) |
    //   denom f32 [N][4] | cnt [N] | offs [N+1] | cursor [N] | perm [E] | bsum/bbase
    char* ws = (char*)d_ws;
    unsigned short* outj = (unsigned short*)ws;
    float* expa  = (float*)(ws + (size_t)NE * 512);
    float* denom = (float*)(ws + (size_t)NE * 512 + (size_t)NE * 16);
    int*   cnt    = (int*)(denom + (size_t)NN * 4);
    int*   offs   = cnt + NN;
    int*   cursor = offs + NN + 1;
    int*   perm   = cursor + NN;
    int*   bsum   = perm + NE;
    int*   bbase  = bsum + NB;

    // one memset covers denom (NN*4 floats) + cnt (NN ints), adjacent
    hipMemsetAsync(denom, 0, (size_t)NN * 5 * sizeof(int), stream);

    k_hist <<<dim3((NE + 255) / 256), dim3(256), 0, stream>>>(eidx, cnt);
    k_scanA<<<dim3(NB), dim3(256), 0, stream>>>(cnt, offs, bsum);
    k_scanB<<<dim3(1), dim3(128), 0, stream>>>(bsum, bbase);
    k_scanC<<<dim3(NB), dim3(256), 0, stream>>>(offs, bbase, cursor);
    k_place<<<dim3((NE + 255) / 256), dim3(256), 0, stream>>>(eidx, cursor, perm);

    k_edge<<<dim3(512), dim3(512), 0, stream>>>(
        x, ea, W, att, bn_g, bn_b, bn_m, bn_v, eidx, outj, expa, denom);

    k_aggr<<<dim3((NN + 3) / 4), dim3(256), 0, stream>>>(
        offs, perm, outj, expa, denom, bias, out);
}

// Round 9
// 321.071 us; speedup vs baseline: 1.8462x; 1.0070x over previous
//
#include <hip/hip_runtime.h>
#include <hip/hip_bf16.h>
#include <math.h>

#define NN 25000
#define NE 250000
#define DD 64
#define HH 4
#define NGROUP (NE / 16)   // 15625 16-edge groups
#define NB 98              // ceil(NN/256) scan blocks

typedef __attribute__((ext_vector_type(8))) short bf16x8;
typedef __attribute__((ext_vector_type(4))) float f32x4;

#define WT_LD 136   // 128 + 8 pad (shorts) -> 272B row stride, 2-way LDS conflict (free)

__device__ __forceinline__ float softplus_f(float x) {
    return fmaxf(x, 0.0f) + __logf(1.0f + __expf(-fabsf(x)));
}

__device__ __forceinline__ unsigned short f2bf(float f) {
    __hip_bfloat16 h = __float2bfloat16(f);
    unsigned short u;
    __builtin_memcpy(&u, &h, 2);
    return u;
}

__device__ __forceinline__ float bf2f(unsigned short u) {
    return __uint_as_float(((unsigned int)u) << 16);
}

// Load 8 consecutive floats, split each into bf16 hi + bf16 lo (compensated).
__device__ __forceinline__ void load8(const float* p, bf16x8& hi, bf16x8& lo) {
    float4 a = *(const float4*)p;
    float4 b = *(const float4*)(p + 4);
    float v[8] = {a.x, a.y, a.z, a.w, b.x, b.y, b.z, b.w};
#pragma unroll
    for (int i = 0; i < 8; ++i) {
        unsigned short h = f2bf(v[i]);
        hi[i] = (short)h;
        lo[i] = (short)f2bf(v[i] - bf2f(h));
    }
}

// ===== k_edge: round-6 body (166us measured) with ONE structural change =====
// Edges are processed in perm (node-sorted) order; outj/expa are stored by
// sorted POSITION so the aggregation pass is a pure sequential stream.
// x_i gathers become node-clustered -> better L1/L2 hit on the latency chain.
// DO NOT restructure the nt-loop/epilogue: allocation is fragile at the
// 128-unified-regs/wave boundary of (512,4) (r3/r7 spill: watch FETCH/WRITE).
__global__ __launch_bounds__(512, 4)
void k_edge(const float* __restrict__ x, const float* __restrict__ ea,
            const float* __restrict__ W, const float* __restrict__ att,
            const float* __restrict__ bn_g, const float* __restrict__ bn_b,
            const float* __restrict__ bn_m, const float* __restrict__ bn_v,
            const int* __restrict__ eidx, const int* __restrict__ perm,
            unsigned short* __restrict__ outj,
            float* __restrict__ expa, float* __restrict__ denom)
{
    __shared__ unsigned short Wsh[256 * WT_LD];  // W^T bf16 [n][k], padded
    __shared__ float attI[256], attJ[256];

    const int tid = threadIdx.x;
    const int lane = tid & 63;
    const int q = lane >> 4;      // quad 0..3
    const int r = lane & 15;

    // Stage W^T (coalesced read of W[k*256+n], n fast-varying).
    for (int idx = tid; idx < 32768; idx += 512) {
        int k = idx >> 8, n = idx & 255;
        Wsh[n * WT_LD + k] = f2bf(W[idx]);
    }
    if (tid < 256) {
        int c = tid;
        attI[c] = att[(c >> 6) * 128 + (c & 63)];
        attJ[c] = att[(c >> 6) * 128 + 64 + (c & 63)];
    }
    float bnsc[HH], bnsh[HH];
#pragma unroll
    for (int t = 0; t < HH; ++t) {
        float inv = rsqrtf(bn_v[t] + 1e-5f);
        bnsc[t] = bn_g[t] * inv;
        bnsh[t] = bn_b[t] - bn_m[t] * bn_g[t] * inv;
    }
    __syncthreads();

    const int gw = blockIdx.x * 8 + (tid >> 6);
    const int nw = gridDim.x * 8;

    for (int g = gw; g < NGROUP; g += nw) {
        const int e0 = g * 16;                 // sorted-position base
        const int pe = perm[e0 + r];           // edge id at this position
        const int ei = eidx[pe];               // target node (sorted-clustered)
        const int ej = eidx[NE + pe];
        const float* xi = x + (size_t)ei * DD;
        const float* xj = x + (size_t)ej * DD;
        const float* ev = ea + (size_t)pe * DD;

        bf16x8 Ahi[6], Alo[6];  // 0,1: x_i k-tiles; 2,3: x_j; 4,5: ea
        load8(xi + q * 8,      Ahi[0], Alo[0]);
        load8(xi + 32 + q * 8, Ahi[1], Alo[1]);
        load8(xj + q * 8,      Ahi[2], Alo[2]);
        load8(xj + 32 + q * 8, Ahi[3], Alo[3]);
        load8(ev + q * 8,      Ahi[4], Alo[4]);
        load8(ev + 32 + q * 8, Ahi[5], Alo[5]);

        float lg[4][4];  // [reg][head]
#pragma unroll
        for (int a = 0; a < 4; ++a)
#pragma unroll
            for (int b = 0; b < 4; ++b) lg[a][b] = 0.f;

        // ---- fused MFMA + epilogue: iteration nt handles col-tiles
        // {nt+4h | h=0..3} (one col per head per lane -> one ushort4 store) ----
#pragma unroll
        for (int nt = 0; nt < 4; ++nt) {
            f32x4 ai[4], aj[4];
#pragma unroll
            for (int h = 0; h < 4; ++h) {
                ai[h] = (f32x4){0.f, 0.f, 0.f, 0.f};
                aj[h] = (f32x4){0.f, 0.f, 0.f, 0.f};
            }
#pragma unroll
            for (int h = 0; h < 4; ++h) {
                const unsigned short* bp = &Wsh[((nt + 4 * h) * 16 + r) * WT_LD + q * 8];
#pragma unroll
                for (int kt = 0; kt < 4; ++kt) {
                    bf16x8 bf = *(const bf16x8*)(bp + kt * 32);
                    const int fi = (kt < 2) ? kt : kt + 2;  // x_i, x_i, ea, ea
                    const int fj = kt + 2;                  // x_j, x_j, ea, ea
                    ai[h] = __builtin_amdgcn_mfma_f32_16x16x32_bf16(Ahi[fi], bf, ai[h], 0, 0, 0);
                    ai[h] = __builtin_amdgcn_mfma_f32_16x16x32_bf16(Alo[fi], bf, ai[h], 0, 0, 0);
                    aj[h] = __builtin_amdgcn_mfma_f32_16x16x32_bf16(Ahi[fj], bf, aj[h], 0, 0, 0);
                    aj[h] = __builtin_amdgcn_mfma_f32_16x16x32_bf16(Alo[fj], bf, aj[h], 0, 0, 0);
                }
            }
            // consume: softplus, att partials, pack+store outj (acc dies here)
            const int dbase = nt * 16 + r;   // dim index d for this lane
#pragma unroll
            for (int reg = 0; reg < 4; ++reg) {
                ushort4 pk;
                unsigned short* pkp = (unsigned short*)&pk;
#pragma unroll
                for (int h = 0; h < 4; ++h) {
                    const int c = dbase + 64 * h;
                    float spi = softplus_f(ai[h][reg]);
                    float spj = softplus_f(aj[h][reg]);
                    lg[reg][h] += spi * attI[c] + spj * attJ[c];
                    pkp[h] = f2bf(spj);
                }
                const unsigned p = (unsigned)(e0 + q * 4 + reg);  // sorted position
                *(ushort4*)&outj[p * 256 + dbase * 4] = pk;
            }
        }

        // ---- logit reduce + BN + exp + denom ----
#pragma unroll
        for (int off = 1; off < 16; off <<= 1) {
#pragma unroll
            for (int a = 0; a < 4; ++a)
#pragma unroll
                for (int b = 0; b < 4; ++b)
                    lg[a][b] += __shfl_xor(lg[a][b], off, 64);
        }
        float exv[4][4];
#pragma unroll
        for (int reg = 0; reg < 4; ++reg)
#pragma unroll
            for (int h = 0; h < 4; ++h)
                exv[reg][h] = __expf(softplus_f(fmaf(lg[reg][h], bnsc[h], bnsh[h])));

        // target-node ids for this quad's 4 edges (shfl while ALL lanes active)
        int iis[4];
#pragma unroll
        for (int reg = 0; reg < 4; ++reg)
            iis[reg] = __shfl(ei, q * 4 + reg, 16);  // within-quad lane m holds edge m

        if (r < 4) {  // lane r handles head r for its quad's 4 edges
#pragma unroll
            for (int reg = 0; reg < 4; ++reg) {
                const int p = e0 + q * 4 + reg;      // sorted position
                expa[p * 4 + r] = exv[reg][r];
                atomicAdd(&denom[iis[reg] * 4 + r], exv[reg][r]);
            }
        }
    }
}

// ===== counting sort of edges by target node (multi-CU scan) =====
__global__ __launch_bounds__(256)
void k_hist(const int* __restrict__ eidx, int* __restrict__ cnt) {
    const int e = blockIdx.x * 256 + threadIdx.x;
    if (e < NE) atomicAdd(&cnt[eidx[e]], 1);
}

__global__ __launch_bounds__(256)
void k_scanA(const int* __restrict__ cnt, int* __restrict__ offs,
             int* __restrict__ bsum) {
    __shared__ int s[256];
    const int tid = threadIdx.x;
    const int i = blockIdx.x * 256 + tid;
    int v = (i < NN) ? cnt[i] : 0;
    s[tid] = v;
    __syncthreads();
#pragma unroll
    for (int off = 1; off < 256; off <<= 1) {
        int t = (tid >= off) ? s[tid - off] : 0;
        __syncthreads();
        s[tid] += t;
        __syncthreads();
    }
    if (i < NN) offs[i] = s[tid] - v;
    if (tid == 255) bsum[blockIdx.x] = s[255];
}

__global__ __launch_bounds__(128)
void k_scanB(const int* __restrict__ bsum, int* __restrict__ bbase) {
    __shared__ int s[128];
    const int tid = threadIdx.x;
    int v = (tid < NB) ? bsum[tid] : 0;
    s[tid] = v;
    __syncthreads();
#pragma unroll
    for (int off = 1; off < 128; off <<= 1) {
        int t = (tid >= off) ? s[tid - off] : 0;
        __syncthreads();
        s[tid] += t;
        __syncthreads();
    }
    if (tid < NB) bbase[tid] = s[tid] - v;
}

__global__ __launch_bounds__(256)
void k_scanC(int* __restrict__ offs, const int* __restrict__ bbase,
             int* __restrict__ cursor) {
    const int i = blockIdx.x * 256 + threadIdx.x;
    if (i < NN) {
        const int o = offs[i] + bbase[blockIdx.x];
        offs[i] = o;
        cursor[i] = o;
    }
    if (i == 0) offs[NN] = NE;
}

__global__ __launch_bounds__(256)
void k_place(const int* __restrict__ eidx, int* __restrict__ cursor,
             int* __restrict__ perm) {
    const int e = blockIdx.x * 256 + threadIdx.x;
    if (e < NE) {
        const int pos = atomicAdd(&cursor[eidx[e]], 1);
        perm[pos] = e;
    }
}

// One wave per node, lane = dim d. outj/expa are stored in sorted position
// order -> this is a PURE SEQUENTIAL STREAM (no perm indirection, no atomics).
__global__ __launch_bounds__(256)
void k_aggr(const int* __restrict__ offs,
            const unsigned short* __restrict__ outj,
            const float* __restrict__ expa,
            const float* __restrict__ denom,
            const float* __restrict__ bias,
            float* __restrict__ out)
{
    const int n = blockIdx.x * 4 + (threadIdx.x >> 6);
    if (n >= NN) return;
    const int lane = threadIdx.x & 63;
    const int k0 = offs[n], k1 = offs[n + 1];
    const float4 dv = *(const float4*)&denom[n * 4];
    float num0 = 0.f, num1 = 0.f, num2 = 0.f, num3 = 0.f;
    for (int k = k0; k < k1; ++k) {
        const float4 ex = *(const float4*)&expa[k * 4];
        const ushort4 v = *(const ushort4*)&outj[((unsigned)k << 8) | (lane << 2)];
        num0 += ex.x * bf2f(v.x);
        num1 += ex.y * bf2f(v.y);
        num2 += ex.z * bf2f(v.z);
        num3 += ex.w * bf2f(v.w);
    }
    float r = 0.f;
    r += (dv.x > 0.f) ? num0 / dv.x : 0.f;
    r += (dv.y > 0.f) ? num1 / dv.y : 0.f;
    r += (dv.z > 0.f) ? num2 / dv.z : 0.f;
    r += (dv.w > 0.f) ? num3 / dv.w : 0.f;
    out[n * DD + lane] = 0.25f * r + bias[lane];
}

extern "C" void kernel_launch(void* const* d_in, const int* in_sizes, int n_in,
                              void* d_out, int out_size, void* d_ws, size_t ws_size,
                              hipStream_t stream)
{
    (void)in_sizes; (void)n_in; (void)out_size; (void)ws_size;
    const float* x    = (const float*)d_in[0];
    const float* ea   = (const float*)d_in[1];
    const float* W    = (const float*)d_in[2];
    const float* att  = (const float*)d_in[3];
    const float* bias = (const float*)d_in[4];
    const float* bn_g = (const float*)d_in[5];
    const float* bn_b = (const float*)d_in[6];
    const float* bn_m = (const float*)d_in[7];
    const float* bn_v = (const float*)d_in[8];
    const int*   eidx = (const int*)d_in[9];
    float* out = (float*)d_out;

    // ws layout: outj bf16 [E][64][4] (128 MB) | expa f32 [E][4] (4 MB) |
    //   denom f32 [N][4] | cnt [N] | offs [N+1] | cursor [N] | perm [E] | bsum/bbase
    char* ws = (char*)d_ws;
    unsigned short* outj = (unsigned short*)ws;
    float* expa  = (float*)(ws + (size_t)NE * 512);
    float* denom = (float*)(ws + (size_t)NE * 512 + (size_t)NE * 16);
    int*   cnt    = (int*)(denom + (size_t)NN * 4);
    int*   offs   = cnt + NN;
    int*   cursor = offs + NN + 1;
    int*   perm   = cursor + NN;
    int*   bsum   = perm + NE;
    int*   bbase  = bsum + NB;

    // one memset covers denom (NN*4 floats) + cnt (NN ints), adjacent
    hipMemsetAsync(denom, 0, (size_t)NN * 5 * sizeof(int), stream);

    k_hist <<<dim3((NE + 255) / 256), dim3(256), 0, stream>>>(eidx, cnt);
    k_scanA<<<dim3(NB), dim3(256), 0, stream>>>(cnt, offs, bsum);
    k_scanB<<<dim3(1), dim3(128), 0, stream>>>(bsum, bbase);
    k_scanC<<<dim3(NB), dim3(256), 0, stream>>>(offs, bbase, cursor);
    k_place<<<dim3((NE + 255) / 256), dim3(256), 0, stream>>>(eidx, cursor, perm);

    k_edge<<<dim3(512), dim3(512), 0, stream>>>(
        x, ea, W, att, bn_g, bn_b, bn_m, bn_v, eidx, perm, outj, expa, denom);

    k_aggr<<<dim3((NN + 3) / 4), dim3(256), 0, stream>>>(
        offs, outj, expa, denom, bias, out);
}